// Round 4
// baseline (312.138 us; speedup 1.0000x reference)
//
#include <hip/hip_runtime.h>
#include <hip/hip_bf16.h>
#include <stdint.h>

// Problem constants
constexpr int IN_DIM   = 2048;
constexpr int OUT_DIM  = 2048;
constexpr int BATCH    = 4096;
constexpr int KDIM     = 2 * IN_DIM;   // concatenated K: [xn | S] vs [scale_base | Wd]
constexpr float LN_EPS = 1e-5f;

#define TILE 128
#define BK   64
constexpr int NK    = KDIM / BK;       // 64 k-steps
constexpr int STAGE = TILE * BK;       // shorts per matrix per stage (16 KB)

typedef __attribute__((ext_vector_type(8))) short  short8;  // 8 x bf16 (4 VGPRs)
typedef __attribute__((ext_vector_type(4))) float  f32x4;   // MFMA accumulator

__device__ __forceinline__ unsigned short f2bf(float f) {
  __hip_bfloat16 h = __float2bfloat16(f);
  return *reinterpret_cast<unsigned short*>(&h);
}
__device__ __forceinline__ unsigned pack2bf(float a, float b) {
  return (unsigned)f2bf(a) | ((unsigned)f2bf(b) << 16);
}

// ---------------------------------------------------------------------------
// Kernel 1: LayerNorm + RBF basis-sum. One block (256 thr) per batch row.
// Writes bf16 A = [xn | S] row-major (BATCH x KDIM).
// ---------------------------------------------------------------------------
__global__ __launch_bounds__(256) void ln_rbf_kernel(
    const float* __restrict__ x, const float* __restrict__ lnw,
    const float* __restrict__ lnb, const float* __restrict__ betap,
    const float* __restrict__ grid, unsigned short* __restrict__ A)
{
  const int row = blockIdx.x;
  const int tid = threadIdx.x;
  const float4* xr = reinterpret_cast<const float4*>(x + (size_t)row * IN_DIM);
  float4 v0 = xr[tid];
  float4 v1 = xr[tid + 256];
  float s = (v0.x + v0.y) + (v0.z + v0.w) + (v1.x + v1.y) + (v1.z + v1.w);
  float q = v0.x * v0.x + v0.y * v0.y + v0.z * v0.z + v0.w * v0.w
          + v1.x * v1.x + v1.y * v1.y + v1.z * v1.z + v1.w * v1.w;
  #pragma unroll
  for (int off = 32; off > 0; off >>= 1) {
    s += __shfl_down(s, off, 64);
    q += __shfl_down(q, off, 64);
  }
  __shared__ float red[10];
  const int lane = tid & 63, wv = tid >> 6;
  if (lane == 0) { red[wv] = s; red[4 + wv] = q; }
  __syncthreads();
  if (tid == 0) {
    float ts = (red[0] + red[1]) + (red[2] + red[3]);
    float tq = (red[4] + red[5]) + (red[6] + red[7]);
    float mu  = ts * (1.0f / IN_DIM);
    float var = tq * (1.0f / IN_DIM) - mu * mu;
    red[8] = mu;
    red[9] = rsqrtf(var + LN_EPS);
  }
  __syncthreads();
  const float mu = red[8], rs = red[9];
  const float beta = fminf(fmaxf(betap[0], 0.5f), 6.0f);
  float g[8];
  #pragma unroll
  for (int i = 0; i < 8; i++) g[i] = grid[i];
  const float4* w4 = reinterpret_cast<const float4*>(lnw);
  const float4* b4 = reinterpret_cast<const float4*>(lnb);
  unsigned short* Ar = A + (size_t)row * KDIM;
  #pragma unroll
  for (int h = 0; h < 2; h++) {
    const int idx = tid + h * 256;        // float4 index within the row
    float4 xv  = (h == 0) ? v0 : v1;
    float4 wv4 = w4[idx];
    float4 bv4 = b4[idx];
    float xa[4] = {xv.x, xv.y, xv.z, xv.w};
    float wa[4] = {wv4.x, wv4.y, wv4.z, wv4.w};
    float ba[4] = {bv4.x, bv4.y, bv4.z, bv4.w};
    float xn[4], S[4];
    #pragma unroll
    for (int c = 0; c < 4; c++) {
      float xnv = (xa[c] - mu) * rs * wa[c] + ba[c];
      xn[c] = xnv;
      float acc = 0.f;
      #pragma unroll
      for (int gg = 0; gg < 8; gg++) {
        float d = xnv - g[gg];
        acc += __expf(-beta * d * d);
      }
      S[c] = acc;
    }
    uint2 px, ps;
    px.x = pack2bf(xn[0], xn[1]);
    px.y = pack2bf(xn[2], xn[3]);
    ps.x = pack2bf(S[0], S[1]);
    ps.y = pack2bf(S[2], S[3]);
    *reinterpret_cast<uint2*>(Ar + idx * 4) = px;
    *reinterpret_cast<uint2*>(Ar + IN_DIM + idx * 4) = ps;
  }
}

// ---------------------------------------------------------------------------
// Kernel 2: pack bf16 B = [scale_base | Wd], Wd[o,i] = sum_g spline_weight.
// Fully-coalesced: one float4 per lane, shfl_xor/shfl_down g-reduction.
// ---------------------------------------------------------------------------
constexpr int SW_F4   = OUT_DIM * IN_DIM * 2;   // float4 count of spline_weight
constexpr int SB_F4   = OUT_DIM * IN_DIM / 4;   // float4 count of scale_base

__global__ __launch_bounds__(256) void pack_b_kernel(
    const float* __restrict__ sw, const float* __restrict__ sb,
    unsigned* __restrict__ Bu)    // B as uint (2 bf16 per uint), OUT x KDIM/2
{
  const int g = blockIdx.x * 256 + threadIdx.x;
  const int lane = threadIdx.x & 63;
  if (g < SW_F4) {
    float4 v = reinterpret_cast<const float4*>(sw)[g];
    float s = (v.x + v.y) + (v.z + v.w);
    s += __shfl_xor(s, 1, 64);                 // full Wd[i] in both lanes of pair
    float hi = __shfl_down(s, 2, 64);          // Wd of i+1 for even-pair lanes
    if ((lane & 3) == 0) {
      const int i_lin = g >> 1;                // linear (o,i)
      const int o = i_lin >> 11;               // / IN_DIM
      const int i = i_lin & (IN_DIM - 1);
      Bu[(size_t)o * (KDIM / 2) + (IN_DIM / 2) + (i >> 1)] = pack2bf(s, hi);
    }
  } else {
    const int t = g - SW_F4;                   // [0, SB_F4)
    float4 v = reinterpret_cast<const float4*>(sb)[t];
    const int o  = t >> 9;                     // 512 float4 per sb row
    const int i4 = t & 511;
    uint2 u;
    u.x = pack2bf(v.x, v.y);
    u.y = pack2bf(v.z, v.w);
    *reinterpret_cast<uint2*>(&Bu[(size_t)o * (KDIM / 2) + i4 * 2]) = u;
  }
}

// ---------------------------------------------------------------------------
// Kernel 3: C = A @ B^T + bias. PRODUCER-CONSUMER wave specialization.
// 512 thr = 8 waves. Waves 0-3: consumers (2x2 of 64x64, 4x4 MFMA accs,
// NO __syncthreads in K-loop). Waves 4-7: producers (all global_load_lds +
// their own vmcnt(0) drains). 2-slot LDS ring (64 KB -> 2 blocks/CU).
// Handoff: monotone LDS counters, workgroup-scope acquire/release atomics.
//   prod_done: +1 per producer wave per stage completed (data resident).
//   cons_done: +1 per consumer wave per stage fully consumed.
// Consumer reads stage kt when prod_done >= 4*(kt+1).
// Producer writes stage kt (kt>=2, reusing slot of kt-2) when
// cons_done >= 4*(kt-1). All sync intra-block => dispatch-order safe (G16).
// ---------------------------------------------------------------------------
__device__ __forceinline__ void gld_lds16(const unsigned short* g, unsigned short* l) {
  __builtin_amdgcn_global_load_lds(
      (const __attribute__((address_space(1))) void*)g,
      (__attribute__((address_space(3))) void*)l, 16, 0, 0);
}

__global__ __launch_bounds__(512) void gemm_kernel(
    const unsigned short* __restrict__ A, const unsigned short* __restrict__ Bm,
    const float* __restrict__ bias, float* __restrict__ out)
{
  __shared__ __align__(16) unsigned short As[2 * STAGE];   // 32 KB
  __shared__ __align__(16) unsigned short Bs[2 * STAGE];   // 32 KB
  __shared__ unsigned prod_done, cons_done;

  const int tid  = threadIdx.x;
  const int lane = tid & 63;
  const int wv   = tid >> 6;       // 0..7
  const int m0   = blockIdx.y * TILE;
  const int n0   = blockIdx.x * TILE;

  if (tid == 0) { prod_done = 0u; cons_done = 0u; }
  __syncthreads();                 // flags visible; the ONLY block barrier

  if (wv >= 4) {
    // ----------------------- PRODUCER (waves 4-7) -----------------------
    const int p = wv - 4;
    // Swizzle folded into the GLOBAL fetch address (global_load_lds dest is
    // wave-uniform base + lane*16 [m104/m108]). Logical (row, col8) lives at
    // LDS slot row*8 + (col8 ^ (row&7)).
    const unsigned short* Ap[4];
    const unsigned short* Bp[4];
    unsigned short* lA[4];
    unsigned short* lB[4];
    #pragma unroll
    for (int j = 0; j < 4; j++) {
      const int seg  = j * 256 + p * 64 + lane;
      const int row  = seg >> 3;
      const int gcol = ((seg & 7) ^ (row & 7)) * 8;
      Ap[j] = A  + (size_t)(m0 + row) * KDIM + gcol;
      Bp[j] = Bm + (size_t)(n0 + row) * KDIM + gcol;
      lA[j] = &As[(j * 256 + p * 64) * 8];
      lB[j] = &Bs[(j * 256 + p * 64) * 8];
    }
    #pragma unroll 1
    for (int kt = 0; kt < NK; kt++) {
      if (kt >= 2) {
        const unsigned need = 4u * (unsigned)(kt - 1);  // kt-2 fully consumed
        while (__hip_atomic_load(&cons_done, __ATOMIC_ACQUIRE,
                                 __HIP_MEMORY_SCOPE_WORKGROUP) < need)
          __builtin_amdgcn_s_sleep(1);
      }
      const int slot = (kt & 1) * STAGE;
      const int koff = kt * BK;
      #pragma unroll
      for (int j = 0; j < 4; j++) gld_lds16(Ap[j] + koff, lA[j] + slot);
      #pragma unroll
      for (int j = 0; j < 4; j++) gld_lds16(Bp[j] + koff, lB[j] + slot);
      __builtin_amdgcn_s_waitcnt(0);            // drain OWN loads only
      if (lane == 0)
        __hip_atomic_fetch_add(&prod_done, 1u, __ATOMIC_RELEASE,
                               __HIP_MEMORY_SCOPE_WORKGROUP);
    }
    return;
  }

  // ------------------------- CONSUMER (waves 0-3) -------------------------
  const int wr   = wv >> 1;        // 2x2 wave grid over the 128x128 tile
  const int wc   = wv & 1;
  const int lrow = lane & 15;      // fragment m / n index
  const int lkq  = lane >> 4;      // k-quarter within a 16-B-granule row

  f32x4 acc[4][4] = {};

  #pragma unroll 1
  for (int kt = 0; kt < NK; kt++) {
    const unsigned need = 4u * (unsigned)(kt + 1);
    while (__hip_atomic_load(&prod_done, __ATOMIC_ACQUIRE,
                             __HIP_MEMORY_SCOPE_WORKGROUP) < need)
      __builtin_amdgcn_s_sleep(1);
    const int cur = (kt & 1) * STAGE;

    short8 af[2][4], bf[2][4];
    #pragma unroll
    for (int h = 0; h < 2; h++) {
      #pragma unroll
      for (int mi = 0; mi < 4; mi++) {
        const int r = wr * 64 + mi * 16 + lrow;
        af[h][mi] = *reinterpret_cast<const short8*>(
            &As[cur + r * BK + (((h << 2) | lkq) ^ (lrow & 7)) * 8]);
      }
      #pragma unroll
      for (int ni = 0; ni < 4; ni++) {
        const int r = wc * 64 + ni * 16 + lrow;
        bf[h][ni] = *reinterpret_cast<const short8*>(
            &Bs[cur + r * BK + (((h << 2) | lkq) ^ (lrow & 7)) * 8]);
      }
    }
    #pragma unroll
    for (int h = 0; h < 2; h++)
      #pragma unroll
      for (int mi = 0; mi < 4; mi++)
        #pragma unroll
        for (int ni = 0; ni < 4; ni++)
          acc[mi][ni] = __builtin_amdgcn_mfma_f32_16x16x32_bf16(
              af[h][mi], bf[h][ni], acc[mi][ni], 0, 0, 0);

    if (lane == 0)
      __hip_atomic_fetch_add(&cons_done, 1u, __ATOMIC_RELEASE,
                             __HIP_MEMORY_SCOPE_WORKGROUP);
  }

  // Epilogue: C/D layout col=lane&15, row=(lane>>4)*4+reg  [measured m89/m91]
  const int rb = (lane >> 4) * 4;
  #pragma unroll
  for (int ni = 0; ni < 4; ni++) {
    const int col = n0 + wc * 64 + ni * 16 + lrow;
    const float bv = bias[col];
    #pragma unroll
    for (int mi = 0; mi < 4; mi++) {
      const int rowm = m0 + wr * 64 + mi * 16 + rb;
      #pragma unroll
      for (int r = 0; r < 4; r++)
        out[(size_t)(rowm + r) * OUT_DIM + col] = acc[mi][ni][r] + bv;
    }
  }
}

// ---------------------------------------------------------------------------
extern "C" void kernel_launch(void* const* d_in, const int* in_sizes, int n_in,
                              void* d_out, int out_size, void* d_ws, size_t ws_size,
                              hipStream_t stream) {
  const float* x    = (const float*)d_in[0];
  const float* lnw  = (const float*)d_in[1];
  const float* lnb  = (const float*)d_in[2];
  const float* sw   = (const float*)d_in[3];   // (OUT, IN, 8)
  const float* sb   = (const float*)d_in[4];   // (OUT, IN)
  const float* bias = (const float*)d_in[5];   // (OUT,)
  const float* beta = (const float*)d_in[6];   // (1,)
  const float* grid = (const float*)d_in[7];   // (8,)
  float* out = (float*)d_out;

  unsigned short* A = (unsigned short*)d_ws;               // BATCH x KDIM bf16 (33.5 MB)
  unsigned short* B = A + (size_t)BATCH * KDIM;            // OUT   x KDIM bf16 (16.8 MB)

  hipLaunchKernelGGL(ln_rbf_kernel, dim3(BATCH), dim3(256), 0, stream,
                     x, lnw, lnb, beta, grid, A);
  hipLaunchKernelGGL(pack_b_kernel, dim3((SW_F4 + SB_F4) / 256), dim3(256), 0, stream,
                     sw, sb, (unsigned*)B);
  hipLaunchKernelGGL(gemm_kernel, dim3(OUT_DIM / TILE, BATCH / TILE), dim3(512), 0, stream,
                     A, B, bias, out);
}